// Round 17
// baseline (880.138 us; speedup 1.0000x reference)
//
#include <hip/hip_runtime.h>
#include <hip/hip_bf16.h>

#define N_TOK 8192
#define DIM   1024
#define HID   4096
#define NEXP  8
#define TOPK  2
#define M_TOT (N_TOK*TOPK)

typedef __bf16 bf16x8 __attribute__((ext_vector_type(8)));
typedef float  f32x4  __attribute__((ext_vector_type(4)));
typedef unsigned short us;

__device__ __forceinline__ us f2bf(float f) {
    union { __hip_bfloat16 h; us u; } c;
    c.h = __float2bfloat16(f);
    return c.u;
}

// async global->LDS, 16B/lane. LDS dest wave-uniform base; lane l -> base + l*16B.
__device__ __forceinline__ void gload16(const us* g, us* l) {
    __builtin_amdgcn_global_load_lds(
        (const __attribute__((address_space(1))) void*)g,
        (__attribute__((address_space(3))) void*)l,
        16, 0, 0);
}

// ---------------------------------------------------------------------------
// Widened tiles at constant per-wave register cost (R16-verified, best):
//   gemm1: 256M x 128N, 8 waves (4M x 2N), each wave 64x64 = acc[4][4]
//   gemm2: 128M x 256N, 8 waves (2M x 4N), each wave 64x64 = acc[4][4]
// BK=32, 2-phase double-buffered stage-early loop (R13-verified schedule).
// LDS granule swizzle (HW-verified R8/R9/R13/R16: SQ_LDS_BANK_CONFLICT=0):
// LDS[row][s] holds granule s ^ ((row>>1)&3); pre-swizzled global source,
// read at slot hi ^ ((fr>>1)&3).  LDS 48KB/block.
// ---------------------------------------------------------------------------
template<int KTOT, int S0, int S1, int S2, int AS, int BS>
__device__ __forceinline__ void kloop(
    const us* __restrict__ p0, const us* __restrict__ p1, const us* __restrict__ p2,
    us* d0, us* d1, us* d2,
    us* As, us* Bs,
    int rowA, int rowB, int g0,
    f32x4 (&acc)[4][4])
{
#define STG(B, K) \
    gload16(p0 + (K), d0 + (B)*S0); \
    gload16(p1 + (K), d1 + (B)*S1); \
    gload16(p2 + (K), d2 + (B)*S2)

#define CMP(B) { \
    bf16x8 af[4], bfr[4]; \
    _Pragma("unroll") \
    for (int m = 0; m < 4; ++m) af[m]  = *(const bf16x8*)&As[(B)*AS + rowA + m*512 + g0]; \
    _Pragma("unroll") \
    for (int n = 0; n < 4; ++n) bfr[n] = *(const bf16x8*)&Bs[(B)*BS + rowB + n*512 + g0]; \
    __builtin_amdgcn_s_setprio(1); \
    _Pragma("unroll") \
    for (int m = 0; m < 4; ++m) \
        _Pragma("unroll") \
        for (int n = 0; n < 4; ++n) \
            acc[m][n] = __builtin_amdgcn_mfma_f32_16x16x32_bf16(af[m], bfr[n], acc[m][n], 0, 0, 0); \
    __builtin_amdgcn_s_setprio(0); }

    STG(0, 0);
    asm volatile("s_waitcnt vmcnt(0)" ::: "memory");
    __builtin_amdgcn_s_barrier();

#pragma unroll 1
    for (int k0 = 0; k0 < KTOT; k0 += 64) {
        STG(1, k0 + 32);
        CMP(0)
        asm volatile("s_waitcnt vmcnt(0)" ::: "memory");
        __builtin_amdgcn_s_barrier();

        if (k0 + 64 < KTOT) { STG(0, k0 + 64); }
        CMP(1)
        asm volatile("s_waitcnt vmcnt(0)" ::: "memory");
        __builtin_amdgcn_s_barrier();
    }
#undef CMP
#undef STG
}

// ---------------- fused fp32 -> bf16 conversion (w1 then w2, one launch) ----------------
__global__ void cvt2_kernel(const float* __restrict__ a, us* __restrict__ oa, int na4,
                            const float* __restrict__ b, us* __restrict__ ob, int nb4)
{
    int i = blockIdx.x * blockDim.x + threadIdx.x;
    int stride = gridDim.x * blockDim.x;
    int ntot = na4 + nb4;
    for (; i < ntot; i += stride) {
        const float4* src; ushort4* dst; int j;
        if (i < na4) { src = (const float4*)a; dst = (ushort4*)oa; j = i; }
        else         { src = (const float4*)b; dst = (ushort4*)ob; j = i - na4; }
        float4 v = src[j];
        ushort4 o;
        o.x = f2bf(v.x); o.y = f2bf(v.y); o.z = f2bf(v.z); o.w = f2bf(v.w);
        dst[j] = o;
    }
}

// ---------------- router: 4 tokens/block (1 per wave); also emits xb bf16 ----------------
__global__ __launch_bounds__(256) void router_kernel(
    const float* __restrict__ x, const float* __restrict__ rw, const float* __restrict__ rb,
    us* __restrict__ xb,
    int* __restrict__ tidx, float* __restrict__ tgate, int* __restrict__ counts)
{
    int t = blockIdx.x * 4 + (threadIdx.x >> 6);
    int lane = threadIdx.x & 63;
    const float4* xr4 = reinterpret_cast<const float4*>(x + (size_t)t * DIM);
    ushort4* xb4 = reinterpret_cast<ushort4*>(xb + (size_t)t * DIM);
    float acc[NEXP];
#pragma unroll
    for (int e = 0; e < NEXP; ++e) acc[e] = 0.f;
#pragma unroll
    for (int i = 0; i < 4; ++i) {
        float4 xv = xr4[lane + 64*i];
        ushort4 o;
        o.x = f2bf(xv.x); o.y = f2bf(xv.y); o.z = f2bf(xv.z); o.w = f2bf(xv.w);
        xb4[lane + 64*i] = o;
#pragma unroll
        for (int e = 0; e < NEXP; ++e) {
            float4 wv = reinterpret_cast<const float4*>(rw + e*DIM)[lane + 64*i];
            acc[e] += xv.x*wv.x + xv.y*wv.y + xv.z*wv.z + xv.w*wv.w;
        }
    }
#pragma unroll
    for (int e = 0; e < NEXP; ++e) {
        float v = acc[e];
#pragma unroll
        for (int off = 32; off >= 1; off >>= 1) v += __shfl_xor(v, off);
        acc[e] = v + rb[e];
    }
    int i0 = 0;
#pragma unroll
    for (int e = 1; e < NEXP; ++e) if (acc[e] > acc[i0]) i0 = e;
    int i1 = (i0 == 0) ? 1 : 0;
#pragma unroll
    for (int e = 0; e < NEXP; ++e) if (e != i0 && acc[e] > acc[i1]) i1 = e;

    float mx = acc[i0];
    float den = 0.f;
    float pe[NEXP];
#pragma unroll
    for (int e = 0; e < NEXP; ++e) { pe[e] = __expf(acc[e] - mx); den += pe[e]; }
    float inv = 1.f / den;
    if (lane == 0) {
        tidx[2*t]   = i0;  tidx[2*t+1]  = i1;
        tgate[2*t]  = pe[i0]*inv; tgate[2*t+1] = pe[i1]*inv;
        atomicAdd(&counts[i0], 1);
        atomicAdd(&counts[i1], 1);
    }
}

__global__ void prefix_kernel(const int* __restrict__ counts, int* __restrict__ offsets) {
    if (threadIdx.x == 0 && blockIdx.x == 0) {
        int s = 0;
        for (int e = 0; e < NEXP; ++e) { offsets[e] = s; s += counts[e]; }
    }
}

__global__ void assign_kernel(const int* __restrict__ tidx, const float* __restrict__ tgate,
                              const int* __restrict__ offsets, int* __restrict__ counts2,
                              int* __restrict__ rowtok, float* __restrict__ rowgate)
{
    int t = blockIdx.x * blockDim.x + threadIdx.x;
    if (t >= N_TOK) return;
#pragma unroll
    for (int k = 0; k < TOPK; ++k) {
        int e = tidx[2*t+k];
        int pos = atomicAdd(&counts2[e], 1);
        int r = offsets[e] + pos;
        rowtok[r]  = t;
        rowgate[r] = tgate[2*t+k];
    }
}

// ---------------- GEMM1 (256x128, 8 waves): hg = gelu(Xg @ w1[e]^T + b1[e]) ----------------
__global__ __launch_bounds__(512) void gemm1_kernel(
    const us* __restrict__ xb,      // N x D bf16
    const us* __restrict__ w1b,     // E x H x D bf16
    const float* __restrict__ b1,   // E x H
    const int* __restrict__ rowtok,
    const int* __restrict__ counts, const int* __restrict__ offsets,
    us* __restrict__ hg)            // M_TOT x H bf16
{
    int e   = blockIdx.z;
    int cnt = counts[e];
    int mt  = blockIdx.y;
    if (mt * 256 >= cnt) return;
    int base  = offsets[e];
    int nbase = blockIdx.x * 128;

    __shared__ us As[16384];   // 2 x [256][32]
    __shared__ us Bs[8192];    // 2 x [128][32]
    __shared__ int rowids[256];

    int tid = threadIdx.x;
    if (tid < 256) {
        int r = mt*256 + tid;
        rowids[tid] = rowtok[base + (r < cnt ? r : cnt - 1)];
    }
    __syncthreads();

    int lane = tid & 63;
    int wid  = tid >> 6;       // 0..7
    int lr   = lane >> 2;
    int sgel = (((lane & 3) ^ ((lane >> 3) & 3)) << 3);   // pre-swizzled source granule

    // staging: wave w -> A chunks 2w,2w+1 (rows 0..255), B chunk w (rows 0..127)
    int sa0 = (2*wid)*16 + lr;
    int sa1 = (2*wid+1)*16 + lr;
    int sb  = wid*16 + lr;

    const us* wE = w1b + (size_t)e * HID * DIM;
    const us* p0 = xb + (size_t)rowids[sa0] * DIM + sgel;
    const us* p1 = xb + (size_t)rowids[sa1] * DIM + sgel;
    const us* p2 = wE + (size_t)(nbase + sb) * DIM + sgel;
    us* d0 = &As[(2*wid)*512];
    us* d1 = &As[(2*wid+1)*512];
    us* d2 = &Bs[wid*512];

    int wm = wid >> 1, wn = wid & 1;   // 4M x 2N
    int fr = lane & 15, hi = lane >> 4;
    int rowA = (wm*64 + fr) * 32;
    int rowB = (wn*64 + fr) * 32;
    int g0 = ((hi ^ ((fr >> 1) & 3)) << 3);

    f32x4 acc[4][4];
#pragma unroll
    for (int m = 0; m < 4; ++m)
#pragma unroll
        for (int n = 0; n < 4; ++n)
#pragma unroll
            for (int j = 0; j < 4; ++j) acc[m][n][j] = 0.f;

    kloop<DIM, 8192, 8192, 4096, 8192, 4096>(p0, p1, p2, d0, d1, d2,
                                             As, Bs, rowA, rowB, g0, acc);

    const float* b1e = b1 + (size_t)e * HID;
#pragma unroll
    for (int m = 0; m < 4; ++m) {
        int rbase = mt*256 + wm*64 + m*16 + hi*4;
#pragma unroll
        for (int j = 0; j < 4; ++j) {
            int grow = rbase + j;
            if (grow < cnt) {
                size_t rowoff = (size_t)(base + grow) * HID;
#pragma unroll
                for (int n = 0; n < 4; ++n) {
                    int col = nbase + wn*64 + n*16 + fr;
                    float v = acc[m][n][j] + b1e[col];
                    float u  = 0.7978845608028654f * (v + 0.044715f * v * v * v);
                    float ex = __expf(2.f * u);
                    float th = 1.f - 2.f / (ex + 1.f);
                    hg[rowoff + col] = f2bf(0.5f * v * (1.f + th));
                }
            }
        }
    }
}

// ---------------- GEMM2 (128x256, 8 waves, full K=4096): y[tok] += gate*(hg @ w2[e]^T + b2[e]) ----------------
__global__ __launch_bounds__(512) void gemm2_kernel(
    const us* __restrict__ hg,      // M_TOT x H bf16
    const us* __restrict__ w2b,     // E x D x H bf16
    const float* __restrict__ b2,   // E x D
    const int* __restrict__ rowtok, const float* __restrict__ rowgate,
    const int* __restrict__ counts, const int* __restrict__ offsets,
    float* __restrict__ y)          // N x D fp32 (pre-zeroed)
{
    int e   = blockIdx.z;
    int cnt = counts[e];
    int mt  = blockIdx.y;
    if (mt * 128 >= cnt) return;
    int base  = offsets[e];
    int nbase = blockIdx.x * 256;

    __shared__ us As[8192];    // 2 x [128][32]
    __shared__ us Bs[16384];   // 2 x [256][32]

    int tid  = threadIdx.x;
    int lane = tid & 63;
    int wid  = tid >> 6;
    int lr   = lane >> 2;
    int sgel = (((lane & 3) ^ ((lane >> 3) & 3)) << 3);

    // staging: wave w -> A chunk w (rows 0..127), B chunks 2w,2w+1 (rows 0..255)
    int sa  = wid*16 + lr;
    int sb0 = (2*wid)*16 + lr;
    int sb1 = (2*wid+1)*16 + lr;

    int ar = mt*128 + sa; if (ar >= cnt) ar = cnt - 1;
    const us* wE = w2b + (size_t)e * DIM * HID;
    const us* p0 = hg + (size_t)(base + ar) * HID + sgel;
    const us* p1 = wE + (size_t)(nbase + sb0) * HID + sgel;
    const us* p2 = wE + (size_t)(nbase + sb1) * HID + sgel;
    us* d0 = &As[wid*512];
    us* d1 = &Bs[(2*wid)*512];
    us* d2 = &Bs[(2*wid+1)*512];

    int wm = wid >> 2, wn = wid & 3;   // 2M x 4N
    int fr = lane & 15, hi = lane >> 4;
    int rowA = (wm*64 + fr) * 32;
    int rowB = (wn*64 + fr) * 32;
    int g0 = ((hi ^ ((fr >> 1) & 3)) << 3);

    f32x4 acc[4][4];
#pragma unroll
    for (int m = 0; m < 4; ++m)
#pragma unroll
        for (int n = 0; n < 4; ++n)
#pragma unroll
            for (int j = 0; j < 4; ++j) acc[m][n][j] = 0.f;

    kloop<HID, 4096, 8192, 8192, 4096, 8192>(p0, p1, p2, d0, d1, d2,
                                             As, Bs, rowA, rowB, g0, acc);

    const float* b2e = b2 + (size_t)e * DIM;
#pragma unroll
    for (int m = 0; m < 4; ++m) {
        int rbase = mt*128 + wm*64 + m*16 + hi*4;
#pragma unroll
        for (int j = 0; j < 4; ++j) {
            int grow = rbase + j;
            if (grow < cnt) {
                int tok = rowtok[base + grow];
                float g = rowgate[base + grow];
#pragma unroll
                for (int n = 0; n < 4; ++n) {
                    int col = nbase + wn*64 + n*16 + fr;
                    float v = acc[m][n][j] + b2e[col];
                    atomicAdd(&y[(size_t)tok * DIM + col], g * v);
                }
            }
        }
    }
}

// ---------------- workspace layout ----------------
static constexpr size_t XB_OFF   = 0;
static constexpr size_t W1B_OFF  = XB_OFF  + (size_t)N_TOK * DIM * 2;
static constexpr size_t W2B_OFF  = W1B_OFF + (size_t)NEXP * HID * DIM * 2;
static constexpr size_t HG_OFF   = W2B_OFF + (size_t)NEXP * DIM * HID * 2;
static constexpr size_t RT_OFF   = HG_OFF  + (size_t)M_TOT * HID * 2;
static constexpr size_t RG_OFF   = RT_OFF  + (size_t)M_TOT * 4;
static constexpr size_t TI_OFF   = RG_OFF  + (size_t)M_TOT * 4;
static constexpr size_t TG_OFF   = TI_OFF  + (size_t)N_TOK * TOPK * 4;
static constexpr size_t META_OFF = TG_OFF  + (size_t)N_TOK * TOPK * 4;
static constexpr size_t WS_NEED  = META_OFF + 256;

extern "C" void kernel_launch(void* const* d_in, const int* in_sizes, int n_in,
                              void* d_out, int out_size, void* d_ws, size_t ws_size,
                              hipStream_t stream)
{
    if (ws_size < WS_NEED) return;

    const float* x  = (const float*)d_in[0];
    const float* rw = (const float*)d_in[1];
    const float* rb = (const float*)d_in[2];
    const float* w1 = (const float*)d_in[3];
    const float* b1 = (const float*)d_in[4];
    const float* w2 = (const float*)d_in[5];
    const float* b2 = (const float*)d_in[6];
    float* y = (float*)d_out;

    char* ws = (char*)d_ws;
    us* xb  = (us*)(ws + XB_OFF);
    us* w1b = (us*)(ws + W1B_OFF);
    us* w2b = (us*)(ws + W2B_OFF);
    us* hg  = (us*)(ws + HG_OFF);
    int*   rowtok  = (int*)  (ws + RT_OFF);
    float* rowgate = (float*)(ws + RG_OFF);
    int*   tidx    = (int*)  (ws + TI_OFF);
    float* tgate   = (float*)(ws + TG_OFF);
    int*   meta    = (int*)  (ws + META_OFF);
    int* counts  = meta;        // 8 ints
    int* counts2 = meta + 8;    // 8 ints
    int* offsets = meta + 16;   // 8 ints

    hipMemsetAsync(meta, 0, 64, stream);
    hipMemsetAsync(y, 0, (size_t)out_size * 4, stream);

    cvt2_kernel<<<2048, 256, 0, stream>>>(w1, w1b, NEXP*HID*DIM/4,
                                          w2, w2b, NEXP*DIM*HID/4);

    router_kernel<<<N_TOK/4, 256, 0, stream>>>(x, rw, rb, xb, tidx, tgate, counts);
    prefix_kernel<<<1, 64, 0, stream>>>(counts, offsets);
    assign_kernel<<<N_TOK/256, 256, 0, stream>>>(tidx, tgate, offsets, counts2, rowtok, rowgate);

    gemm1_kernel<<<dim3(HID/128, 32, NEXP), 512, 0, stream>>>(xb, w1b, b1, rowtok, counts, offsets, hg);
    gemm2_kernel<<<dim3(DIM/256, 128, NEXP), 512, 0, stream>>>(hg, w2b, b2, rowtok, rowgate, counts, offsets, y);
}

// Round 18
// 874.652 us; speedup vs baseline: 1.0063x; 1.0063x over previous
//
#include <hip/hip_runtime.h>
#include <hip/hip_bf16.h>

#define N_TOK 8192
#define DIM   1024
#define HID   4096
#define NEXP  8
#define TOPK  2
#define M_TOT (N_TOK*TOPK)

typedef __bf16 bf16x8 __attribute__((ext_vector_type(8)));
typedef float  f32x4  __attribute__((ext_vector_type(4)));
typedef unsigned short us;

__device__ __forceinline__ us f2bf(float f) {
    union { __hip_bfloat16 h; us u; } c;
    c.h = __float2bfloat16(f);
    return c.u;
}

// async global->LDS, 16B/lane. LDS dest wave-uniform base; lane l -> base + l*16B.
__device__ __forceinline__ void gload16(const us* g, us* l) {
    __builtin_amdgcn_global_load_lds(
        (const __attribute__((address_space(1))) void*)g,
        (__attribute__((address_space(3))) void*)l,
        16, 0, 0);
}

// ---------------------------------------------------------------------------
// Widened tiles at constant per-wave register cost (R16-verified):
//   gemm1: 256M x 128N, 8 waves (4M x 2N), each wave 64x64 = acc[4][4]
//   gemm2: 128M x 256N, 8 waves (2M x 4N), each wave 64x64 = acc[4][4]
// BK=32, 2-phase double-buffered stage-early loop (R13-verified schedule).
// LDS granule swizzle (HW-verified R8/R9/R13/R16: SQ_LDS_BANK_CONFLICT=0):
// LDS[row][s] holds granule s ^ ((row>>1)&3); pre-swizzled global source,
// read at slot hi ^ ((fr>>1)&3).  LDS 48KB/block.
// ---------------------------------------------------------------------------
template<int KTOT, int S0, int S1, int S2, int AS, int BS>
__device__ __forceinline__ void kloop(
    const us* __restrict__ p0, const us* __restrict__ p1, const us* __restrict__ p2,
    us* d0, us* d1, us* d2,
    us* As, us* Bs,
    int rowA, int rowB, int g0,
    f32x4 (&acc)[4][4])
{
#define STG(B, K) \
    gload16(p0 + (K), d0 + (B)*S0); \
    gload16(p1 + (K), d1 + (B)*S1); \
    gload16(p2 + (K), d2 + (B)*S2)

#define CMP(B) { \
    bf16x8 af[4], bfr[4]; \
    _Pragma("unroll") \
    for (int m = 0; m < 4; ++m) af[m]  = *(const bf16x8*)&As[(B)*AS + rowA + m*512 + g0]; \
    _Pragma("unroll") \
    for (int n = 0; n < 4; ++n) bfr[n] = *(const bf16x8*)&Bs[(B)*BS + rowB + n*512 + g0]; \
    __builtin_amdgcn_s_setprio(1); \
    _Pragma("unroll") \
    for (int m = 0; m < 4; ++m) \
        _Pragma("unroll") \
        for (int n = 0; n < 4; ++n) \
            acc[m][n] = __builtin_amdgcn_mfma_f32_16x16x32_bf16(af[m], bfr[n], acc[m][n], 0, 0, 0); \
    __builtin_amdgcn_s_setprio(0); }

    STG(0, 0);
    asm volatile("s_waitcnt vmcnt(0)" ::: "memory");
    __builtin_amdgcn_s_barrier();

#pragma unroll 1
    for (int k0 = 0; k0 < KTOT; k0 += 64) {
        STG(1, k0 + 32);
        CMP(0)
        asm volatile("s_waitcnt vmcnt(0)" ::: "memory");
        __builtin_amdgcn_s_barrier();

        if (k0 + 64 < KTOT) { STG(0, k0 + 64); }
        CMP(1)
        asm volatile("s_waitcnt vmcnt(0)" ::: "memory");
        __builtin_amdgcn_s_barrier();
    }
#undef CMP
#undef STG
}

// ---------------- fused fp32 -> bf16 conversion (w1 then w2, one launch) ----------------
__global__ void cvt2_kernel(const float* __restrict__ a, us* __restrict__ oa, int na4,
                            const float* __restrict__ b, us* __restrict__ ob, int nb4)
{
    int i = blockIdx.x * blockDim.x + threadIdx.x;
    int stride = gridDim.x * blockDim.x;
    int ntot = na4 + nb4;
    for (; i < ntot; i += stride) {
        const float4* src; ushort4* dst; int j;
        if (i < na4) { src = (const float4*)a; dst = (ushort4*)oa; j = i; }
        else         { src = (const float4*)b; dst = (ushort4*)ob; j = i - na4; }
        float4 v = src[j];
        ushort4 o;
        o.x = f2bf(v.x); o.y = f2bf(v.y); o.z = f2bf(v.z); o.w = f2bf(v.w);
        dst[j] = o;
    }
}

// ---------------- router: 4 tokens/block (1 per wave); also emits xb bf16 ----------------
__global__ __launch_bounds__(256) void router_kernel(
    const float* __restrict__ x, const float* __restrict__ rw, const float* __restrict__ rb,
    us* __restrict__ xb,
    int* __restrict__ tidx, float* __restrict__ tgate, int* __restrict__ counts)
{
    int t = blockIdx.x * 4 + (threadIdx.x >> 6);
    int lane = threadIdx.x & 63;
    const float4* xr4 = reinterpret_cast<const float4*>(x + (size_t)t * DIM);
    ushort4* xb4 = reinterpret_cast<ushort4*>(xb + (size_t)t * DIM);
    float acc[NEXP];
#pragma unroll
    for (int e = 0; e < NEXP; ++e) acc[e] = 0.f;
#pragma unroll
    for (int i = 0; i < 4; ++i) {
        float4 xv = xr4[lane + 64*i];
        ushort4 o;
        o.x = f2bf(xv.x); o.y = f2bf(xv.y); o.z = f2bf(xv.z); o.w = f2bf(xv.w);
        xb4[lane + 64*i] = o;
#pragma unroll
        for (int e = 0; e < NEXP; ++e) {
            float4 wv = reinterpret_cast<const float4*>(rw + e*DIM)[lane + 64*i];
            acc[e] += xv.x*wv.x + xv.y*wv.y + xv.z*wv.z + xv.w*wv.w;
        }
    }
#pragma unroll
    for (int e = 0; e < NEXP; ++e) {
        float v = acc[e];
#pragma unroll
        for (int off = 32; off >= 1; off >>= 1) v += __shfl_xor(v, off);
        acc[e] = v + rb[e];
    }
    int i0 = 0;
#pragma unroll
    for (int e = 1; e < NEXP; ++e) if (acc[e] > acc[i0]) i0 = e;
    int i1 = (i0 == 0) ? 1 : 0;
#pragma unroll
    for (int e = 0; e < NEXP; ++e) if (e != i0 && acc[e] > acc[i1]) i1 = e;

    float mx = acc[i0];
    float den = 0.f;
    float pe[NEXP];
#pragma unroll
    for (int e = 0; e < NEXP; ++e) { pe[e] = __expf(acc[e] - mx); den += pe[e]; }
    float inv = 1.f / den;
    if (lane == 0) {
        tidx[2*t]   = i0;  tidx[2*t+1]  = i1;
        tgate[2*t]  = pe[i0]*inv; tgate[2*t+1] = pe[i1]*inv;
        atomicAdd(&counts[i0], 1);
        atomicAdd(&counts[i1], 1);
    }
}

__global__ void prefix_kernel(const int* __restrict__ counts, int* __restrict__ offsets) {
    if (threadIdx.x == 0 && blockIdx.x == 0) {
        int s = 0;
        for (int e = 0; e < NEXP; ++e) { offsets[e] = s; s += counts[e]; }
    }
}

__global__ void assign_kernel(const int* __restrict__ tidx, const float* __restrict__ tgate,
                              const int* __restrict__ offsets, int* __restrict__ counts2,
                              int* __restrict__ rowtok, float* __restrict__ rowgate)
{
    int t = blockIdx.x * blockDim.x + threadIdx.x;
    if (t >= N_TOK) return;
#pragma unroll
    for (int k = 0; k < TOPK; ++k) {
        int e = tidx[2*t+k];
        int pos = atomicAdd(&counts2[e], 1);
        int r = offsets[e] + pos;
        rowtok[r]  = t;
        rowgate[r] = tgate[2*t+k];
    }
}

// ---------------- GEMM1 (256x128, 8 waves): hg = gelu(Xg @ w1[e]^T + b1[e]) ----------------
__global__ __launch_bounds__(512) void gemm1_kernel(
    const us* __restrict__ xb,      // N x D bf16
    const us* __restrict__ w1b,     // E x H x D bf16
    const float* __restrict__ b1,   // E x H
    const int* __restrict__ rowtok,
    const int* __restrict__ counts, const int* __restrict__ offsets,
    us* __restrict__ hg)            // M_TOT x H bf16
{
    int e   = blockIdx.z;
    int cnt = counts[e];
    int mt  = blockIdx.y;
    if (mt * 256 >= cnt) return;
    int base  = offsets[e];
    int nbase = blockIdx.x * 128;

    __shared__ us As[16384];   // 2 x [256][32]
    __shared__ us Bs[8192];    // 2 x [128][32]
    __shared__ int rowids[256];

    int tid = threadIdx.x;
    if (tid < 256) {
        int r = mt*256 + tid;
        rowids[tid] = rowtok[base + (r < cnt ? r : cnt - 1)];
    }
    __syncthreads();

    int lane = tid & 63;
    int wid  = tid >> 6;       // 0..7
    int lr   = lane >> 2;
    int sgel = (((lane & 3) ^ ((lane >> 3) & 3)) << 3);   // pre-swizzled source granule

    // staging: wave w -> A chunks 2w,2w+1 (rows 0..255), B chunk w (rows 0..127)
    int sa0 = (2*wid)*16 + lr;
    int sa1 = (2*wid+1)*16 + lr;
    int sb  = wid*16 + lr;

    const us* wE = w1b + (size_t)e * HID * DIM;
    const us* p0 = xb + (size_t)rowids[sa0] * DIM + sgel;
    const us* p1 = xb + (size_t)rowids[sa1] * DIM + sgel;
    const us* p2 = wE + (size_t)(nbase + sb) * DIM + sgel;
    us* d0 = &As[(2*wid)*512];
    us* d1 = &As[(2*wid+1)*512];
    us* d2 = &Bs[wid*512];

    int wm = wid >> 1, wn = wid & 1;   // 4M x 2N
    int fr = lane & 15, hi = lane >> 4;
    int rowA = (wm*64 + fr) * 32;
    int rowB = (wn*64 + fr) * 32;
    int g0 = ((hi ^ ((fr >> 1) & 3)) << 3);

    f32x4 acc[4][4];
#pragma unroll
    for (int m = 0; m < 4; ++m)
#pragma unroll
        for (int n = 0; n < 4; ++n)
#pragma unroll
            for (int j = 0; j < 4; ++j) acc[m][n][j] = 0.f;

    kloop<DIM, 8192, 8192, 4096, 8192, 4096>(p0, p1, p2, d0, d1, d2,
                                             As, Bs, rowA, rowB, g0, acc);

    const float* b1e = b1 + (size_t)e * HID;
#pragma unroll
    for (int m = 0; m < 4; ++m) {
        int rbase = mt*256 + wm*64 + m*16 + hi*4;
#pragma unroll
        for (int j = 0; j < 4; ++j) {
            int grow = rbase + j;
            if (grow < cnt) {
                size_t rowoff = (size_t)(base + grow) * HID;
#pragma unroll
                for (int n = 0; n < 4; ++n) {
                    int col = nbase + wn*64 + n*16 + fr;
                    float v = acc[m][n][j] + b1e[col];
                    float u  = 0.7978845608028654f * (v + 0.044715f * v * v * v);
                    float ex = __expf(2.f * u);
                    float th = 1.f - 2.f / (ex + 1.f);
                    hg[rowoff + col] = f2bf(0.5f * v * (1.f + th));
                }
            }
        }
    }
}

// ---------------- GEMM2 (128x256, 8 waves, K-split x2): y[tok] += gate*(hg @ w2[e]^T + b2[e]) ----------------
// blockIdx.z = e*2 + ks; each computes a K-half (2048), atomically merged.
__global__ __launch_bounds__(512) void gemm2_kernel(
    const us* __restrict__ hg,      // M_TOT x H bf16
    const us* __restrict__ w2b,     // E x D x H bf16
    const float* __restrict__ b2,   // E x D
    const int* __restrict__ rowtok, const float* __restrict__ rowgate,
    const int* __restrict__ counts, const int* __restrict__ offsets,
    float* __restrict__ y)          // N x D fp32 (pre-zeroed)
{
    int e   = blockIdx.z >> 1;
    int ks  = blockIdx.z & 1;
    int cnt = counts[e];
    int mt  = blockIdx.y;
    if (mt * 128 >= cnt) return;
    int base  = offsets[e];
    int nbase = blockIdx.x * 256;
    int kofs  = ks * (HID/2);

    __shared__ us As[8192];    // 2 x [128][32]
    __shared__ us Bs[16384];   // 2 x [256][32]

    int tid  = threadIdx.x;
    int lane = tid & 63;
    int wid  = tid >> 6;
    int lr   = lane >> 2;
    int sgel = (((lane & 3) ^ ((lane >> 3) & 3)) << 3);

    // staging: wave w -> A chunk w (rows 0..127), B chunks 2w,2w+1 (rows 0..255)
    int sa  = wid*16 + lr;
    int sb0 = (2*wid)*16 + lr;
    int sb1 = (2*wid+1)*16 + lr;

    int ar = mt*128 + sa; if (ar >= cnt) ar = cnt - 1;
    const us* wE = w2b + (size_t)e * DIM * HID + kofs;
    const us* p0 = hg + (size_t)(base + ar) * HID + kofs + sgel;
    const us* p1 = wE + (size_t)(nbase + sb0) * HID + sgel;
    const us* p2 = wE + (size_t)(nbase + sb1) * HID + sgel;
    us* d0 = &As[wid*512];
    us* d1 = &Bs[(2*wid)*512];
    us* d2 = &Bs[(2*wid+1)*512];

    int wm = wid >> 2, wn = wid & 3;   // 2M x 4N
    int fr = lane & 15, hi = lane >> 4;
    int rowA = (wm*64 + fr) * 32;
    int rowB = (wn*64 + fr) * 32;
    int g0 = ((hi ^ ((fr >> 1) & 3)) << 3);

    f32x4 acc[4][4];
#pragma unroll
    for (int m = 0; m < 4; ++m)
#pragma unroll
        for (int n = 0; n < 4; ++n)
#pragma unroll
            for (int j = 0; j < 4; ++j) acc[m][n][j] = 0.f;

    kloop<HID/2, 4096, 8192, 8192, 4096, 8192>(p0, p1, p2, d0, d1, d2,
                                               As, Bs, rowA, rowB, g0, acc);

    const float* b2e = b2 + (size_t)e * DIM;
#pragma unroll
    for (int m = 0; m < 4; ++m) {
        int rbase = mt*128 + wm*64 + m*16 + hi*4;
#pragma unroll
        for (int j = 0; j < 4; ++j) {
            int grow = rbase + j;
            if (grow < cnt) {
                int tok = rowtok[base + grow];
                float g = rowgate[base + grow];
#pragma unroll
                for (int n = 0; n < 4; ++n) {
                    int col = nbase + wn*64 + n*16 + fr;
                    float v = acc[m][n][j] + (ks == 0 ? b2e[col] : 0.f);
                    atomicAdd(&y[(size_t)tok * DIM + col], g * v);
                }
            }
        }
    }
}

// ---------------- workspace layout ----------------
static constexpr size_t XB_OFF   = 0;
static constexpr size_t W1B_OFF  = XB_OFF  + (size_t)N_TOK * DIM * 2;
static constexpr size_t W2B_OFF  = W1B_OFF + (size_t)NEXP * HID * DIM * 2;
static constexpr size_t HG_OFF   = W2B_OFF + (size_t)NEXP * DIM * HID * 2;
static constexpr size_t RT_OFF   = HG_OFF  + (size_t)M_TOT * HID * 2;
static constexpr size_t RG_OFF   = RT_OFF  + (size_t)M_TOT * 4;
static constexpr size_t TI_OFF   = RG_OFF  + (size_t)M_TOT * 4;
static constexpr size_t TG_OFF   = TI_OFF  + (size_t)N_TOK * TOPK * 4;
static constexpr size_t META_OFF = TG_OFF  + (size_t)N_TOK * TOPK * 4;
static constexpr size_t WS_NEED  = META_OFF + 256;

extern "C" void kernel_launch(void* const* d_in, const int* in_sizes, int n_in,
                              void* d_out, int out_size, void* d_ws, size_t ws_size,
                              hipStream_t stream)
{
    if (ws_size < WS_NEED) return;

    const float* x  = (const float*)d_in[0];
    const float* rw = (const float*)d_in[1];
    const float* rb = (const float*)d_in[2];
    const float* w1 = (const float*)d_in[3];
    const float* b1 = (const float*)d_in[4];
    const float* w2 = (const float*)d_in[5];
    const float* b2 = (const float*)d_in[6];
    float* y = (float*)d_out;

    char* ws = (char*)d_ws;
    us* xb  = (us*)(ws + XB_OFF);
    us* w1b = (us*)(ws + W1B_OFF);
    us* w2b = (us*)(ws + W2B_OFF);
    us* hg  = (us*)(ws + HG_OFF);
    int*   rowtok  = (int*)  (ws + RT_OFF);
    float* rowgate = (float*)(ws + RG_OFF);
    int*   tidx    = (int*)  (ws + TI_OFF);
    float* tgate   = (float*)(ws + TG_OFF);
    int*   meta    = (int*)  (ws + META_OFF);
    int* counts  = meta;        // 8 ints
    int* counts2 = meta + 8;    // 8 ints
    int* offsets = meta + 16;   // 8 ints

    hipMemsetAsync(meta, 0, 64, stream);
    hipMemsetAsync(y, 0, (size_t)out_size * 4, stream);

    cvt2_kernel<<<2048, 256, 0, stream>>>(w1, w1b, NEXP*HID*DIM/4,
                                          w2, w2b, NEXP*DIM*HID/4);

    router_kernel<<<N_TOK/4, 256, 0, stream>>>(x, rw, rb, xb, tidx, tgate, counts);
    prefix_kernel<<<1, 64, 0, stream>>>(counts, offsets);
    assign_kernel<<<N_TOK/256, 256, 0, stream>>>(tidx, tgate, offsets, counts2, rowtok, rowgate);

    gemm1_kernel<<<dim3(HID/128, 32, NEXP), 512, 0, stream>>>(xb, w1b, b1, rowtok, counts, offsets, hg);
    gemm2_kernel<<<dim3(DIM/256, 128, NEXP*2), 512, 0, stream>>>(hg, w2b, b2, rowtok, rowgate, counts, offsets, y);
}